// Round 6
// baseline (130.493 us; speedup 1.0000x reference)
//
#include <hip/hip_runtime.h>

// MHA forward, full-bf16 MFMA pipeline.
// ws layout (bytes): xb[8MB] | Wt[6MB: [3][1024][1024] bf16 N-major] | Wot[2MB]
//                    | qkv[24MB: Q,K:[B][H][T][64], V:[B][H][64][T]] | Y[8MB]

typedef short v8s __attribute__((ext_vector_type(8)));
typedef float v4f __attribute__((ext_vector_type(4)));

#define DEVI __device__ __forceinline__

#define B_SZ 2
#define T_SEQ 2048
#define NH 16
#define HS 64
#define CEMB 1024
#define MROWS (B_SZ * T_SEQ)   // 4096
#define KSZ 1024
// Q scale: 1/sqrt(64) * log2(e)  (attention softmax runs in exp2 domain)
#define SCALE_Q 0.18033688011112042f

DEVI unsigned short f2bf(float f) {
  union { float f; unsigned u; } c; c.f = f;
  unsigned u = c.u;
  unsigned r = (u + 0x7FFFu + ((u >> 16) & 1u)) >> 16;   // RNE
  return (unsigned short)r;
}

DEVI float exp2_fast(float x) {         // v_exp_f32 = 2^x
  float r;
  asm("v_exp_f32 %0, %1" : "=v"(r) : "v"(x));
  return r;
}

DEVI unsigned cvt_pk_bf16(float lo, float hi) {  // packs 2 f32 -> 2 bf16
  unsigned r;
  asm("v_cvt_pk_bf16_f32 %0, %1, %2" : "=v"(r) : "v"(lo), "v"(hi));
  return r;
}

// async global -> LDS, 16B per lane (wave-uniform LDS base + lane*16)
DEVI void gload_lds16(const void* g, void* l) {
  __builtin_amdgcn_global_load_lds(
      (const __attribute__((address_space(1))) void*)g,
      (__attribute__((address_space(3))) void*)l, 16, 0, 0);
}

// bijective XCD-contiguous block swizzle (nwg % 8 == 0)
DEVI int xcd_swz(int bid, int nwg) {
  int q = nwg >> 3;
  return (bid & 7) * q + (bid >> 3);
}

// ---------------- x -> bf16 ----------------
__global__ void cvt_f32_bf16x4(const float* __restrict__ in,
                               unsigned short* __restrict__ out, int n4) {
  int i = blockIdx.x * blockDim.x + threadIdx.x;
  if (i >= n4) return;
  float4 v = ((const float4*)in)[i];
  ushort4 o;
  o.x = f2bf(v.x); o.y = f2bf(v.y); o.z = f2bf(v.z); o.w = f2bf(v.w);
  ((ushort4*)out)[i] = o;
}

// ------------- transpose f32[R][C] -> bf16[C][R], per z-slice -------------
__global__ void transpose_cvt(const float* __restrict__ in,
                              unsigned short* __restrict__ out, int R, int C) {
  __shared__ float tile[32][33];
  size_t zoff = (size_t)blockIdx.z * R * C;
  in += zoff; out += zoff;
  int c0 = blockIdx.x * 32, r0 = blockIdx.y * 32;
  int tx = threadIdx.x, ty = threadIdx.y;
#pragma unroll
  for (int j = 0; j < 4; ++j) {
    int r = r0 + ty + j * 8;
    tile[ty + j * 8][tx] = in[(size_t)r * C + c0 + tx];
  }
  __syncthreads();
#pragma unroll
  for (int j = 0; j < 4; ++j) {
    int c = c0 + ty + j * 8;
    out[(size_t)c * R + r0 + tx] = f2bf(tile[tx][ty + j * 8]);
  }
}

// ------------- GEMM: C = A[M][1024] x Bt[N][1024]^T, bf16 in, f32 acc -------
// BM=64 x BN=128 tile, BK=32; grid = nwg 1D with XCD swizzle. 4 waves (2x2),
// per-wave 32x64 = acc[2][4]. 3-deep counted-vmcnt pipeline (vmcnt(6)),
// 36KB LDS -> 4 blocks/CU for TLP. Source chunk pre-swizzled (c ^= row&3),
// same XOR on fragment reads.
// MODE 0: QKV epilogue -> bf16 scatter; Q scaled by SCALE_Q; V transposed
// MODE 1: out-proj epilogue -> f32 [M][1024] + bias
template <int MODE>
__global__ __launch_bounds__(256, 4) void gemm_bt64(
    const unsigned short* __restrict__ A, const unsigned short* __restrict__ Bt,
    void* __restrict__ Cout, const float* __restrict__ bias, int nbx) {
  __shared__ __align__(16) unsigned short As[3][64 * 32];    // 4KB x3
  __shared__ __align__(16) unsigned short Bs[3][128 * 32];   // 8KB x3

  const int tid = threadIdx.x;
  const int lane = tid & 63, w = tid >> 6;
  const int wm = w >> 1, wn = w & 1;
  const int lr = lane & 15, lg = lane >> 4;

  const int wg = xcd_swz(blockIdx.x, gridDim.x);
  const int mb = (wg / nbx) * 64, nb = (wg % nbx) * 128;

  v4f acc[2][4];
  v4f zero = {0.f, 0.f, 0.f, 0.f};
#pragma unroll
  for (int i = 0; i < 2; ++i)
#pragma unroll
    for (int j = 0; j < 4; ++j) acc[i][j] = zero;

  // staging: lane -> row base + (lane>>2), global chunk (lane&3)^(row&3)
  const int srow = lane >> 2;
  const int sgcol = ((lane & 3) ^ (srow & 3)) * 8;
  const unsigned short* gA = A + (size_t)(mb + w * 16 + srow) * KSZ + sgcol;
  const unsigned short* gB = Bt + (size_t)(nb + w * 32 + srow) * KSZ + sgcol;
  unsigned short* lA = &As[0][0] + w * 512;    // wave-uniform; +2048/buf
  unsigned short* lB = &Bs[0][0] + w * 1024;   // wave-uniform; +4096/buf

#define STAGE_G(buf, kb)                                        \
  do {                                                          \
    gload_lds16(gA + (kb), lA + (buf) * 2048);                  \
    gload_lds16(gB + (kb), lB + (buf) * 4096);                  \
    gload_lds16(gB + (kb) + 16 * KSZ, lB + (buf) * 4096 + 512); \
  } while (0)

  // prologue: 3 tiles in flight (9 loads)
  STAGE_G(0, 0);
  STAGE_G(1, 32);
  STAGE_G(2, 64);

  const int NT = KSZ / 32;   // 32 K-steps
  for (int t = 0; t < NT; ++t) {
    // tile t's 3 loads complete (t+1, t+2 outstanding: 6)
    asm volatile("s_waitcnt vmcnt(6)" ::: "memory");
    __builtin_amdgcn_s_barrier();

    const int buf = t % 3;
    v8s af[2], bfr[4];
#pragma unroll
    for (int i = 0; i < 2; ++i) {
      int ra = wm * 32 + i * 16 + lr;
      af[i] = *(const v8s*)&As[buf][ra * 32 + ((lg ^ (lr & 3)) << 3)];
    }
#pragma unroll
    for (int j = 0; j < 4; ++j) {
      int rb = wn * 64 + j * 16 + lr;
      bfr[j] = *(const v8s*)&Bs[buf][rb * 32 + ((lg ^ (lr & 3)) << 3)];
    }
#pragma unroll
    for (int i = 0; i < 2; ++i)
#pragma unroll
      for (int j = 0; j < 4; ++j)
        acc[i][j] = __builtin_amdgcn_mfma_f32_16x16x32_bf16(af[i], bfr[j], acc[i][j], 0, 0, 0);

    // all waves done reading buf before overwriting with tile t+3
    asm volatile("s_waitcnt lgkmcnt(0)" ::: "memory");
    __builtin_amdgcn_s_barrier();
    if (t + 3 < NT) STAGE_G(buf, (t + 3) * 32);
  }
#undef STAGE_G

#pragma unroll
  for (int i = 0; i < 2; ++i) {
    int mrow0 = mb + wm * 32 + i * 16 + lg * 4;
#pragma unroll
    for (int j = 0; j < 4; ++j) {
      int ncol = nb + wn * 64 + j * 16 + lr;
      if (MODE == 0) {
        int p = ncol >> 10, rem = ncol & 1023, h = rem >> 6, d = rem & 63;
        float sc = (p == 0) ? SCALE_Q : 1.0f;
        unsigned short* out = (unsigned short*)Cout;
#pragma unroll
        for (int r = 0; r < 4; ++r) {
          int mrow = mrow0 + r;
          int b = mrow >> 11, t = mrow & 2047;
          size_t off;
          if (p < 2)
            off = ((size_t)((p * B_SZ + b) * NH + h) * T_SEQ + t) * HS + d;
          else  // V transposed: [b][h][d][t]
            off = (size_t)(2 * B_SZ * NH) * T_SEQ * HS +
                  ((size_t)(b * NH + h) * HS + d) * T_SEQ + t;
          out[off] = f2bf(acc[i][j][r] * sc);
        }
      } else {
        float* out = (float*)Cout;
        float bv = bias[ncol];
#pragma unroll
        for (int r = 0; r < 4; ++r)
          out[(size_t)(mrow0 + r) * CEMB + ncol] = acc[i][j][r] + bv;
      }
    }
  }
}

// ------------- causal flash attention, swapped-operand, reg-P -------------
// 512 threads = 8 waves; wave w owns q rows qc*128 + w*16 .. +15.
// mfma(K,Q) -> S^T: lane owns ONE q-row (q=w*16+lr), kv = cf*16+lg*4+r.
// PV uses a CUSTOM k-slot mapping (valid since A/B frags share (lg,j)->k and
// sum over k is order-invariant): call c covers kv in [c*16,c*16+16) u
// [c*16+64,c*16+80); B-frag = lane-local packed {pk(S[c]),pk(S[c+4])} (NO
// cross-lane exchange, no P LDS); A-frag contiguous via permuted V layout:
// col'(kv) = ((kv>>4)&3)*32 + ((kv>>2)&3)*8 + (kv>>6)*4 + (kv&3), XOR-swz.
__global__ __launch_bounds__(512, 4) void attn_kernel(
    const unsigned short* __restrict__ Qg, const unsigned short* __restrict__ Kg,
    const unsigned short* __restrict__ Vtg, unsigned short* __restrict__ Yg) {
  __shared__ __align__(16) unsigned char lds[32 * 1024];
  unsigned char* KsB = lds;             // 16KB [128 s][64 d], chunk-swizzled
  unsigned char* VtB = lds + 16384;     // 16KB [64 d][128 col'], swizzled

  const int tid = threadIdx.x;
  const int lane = tid & 63, w = tid >> 6;
  const int lr = lane & 15, lg = lane >> 4;
  const int qc = 15 - (blockIdx.x >> 5);   // LPT: longest q-chunk first
  const int bh = blockIdx.x & 31;

  const unsigned short* Qbase = Qg + (size_t)bh * T_SEQ * HS;
  const unsigned short* Kbase = Kg + (size_t)bh * T_SEQ * HS;
  const unsigned short* Vtbase = Vtg + (size_t)bh * T_SEQ * HS;  // [64][2048]

  // K staging geometry
  const int ks_row = tid >> 3, ks_cb = tid & 7;
  const int kLds0 = ks_row * 128 + ((ks_cb ^ (ks_row & 7)) << 4);
  const unsigned short* Kg0 = Kbase + ks_row * HS + ks_cb * 8;
  // V staging: thread (vs_d, m) handles col'-chunk m of rows vs_d, vs_d+32
  const int vs_d = tid >> 4, vs_m = tid & 15;
  const int vLds0 = vs_d * 256 + ((vs_m ^ (vs_d & 15)) << 4);
  const int vbt = ((vs_m >> 2) << 4) + ((vs_m & 3) << 2);  // t-offset of 4-group
  const unsigned short* Vg0 = Vtbase + (size_t)vs_d * T_SEQ + vbt;

  // Q fragment (B-operand): lane lr -> q row, lg*8 k-offset
  v8s qA[2];
  {
    const unsigned short* qrow = Qbase + (size_t)(qc * 128 + w * 16 + lr) * HS;
    qA[0] = *(const v8s*)(qrow + lg * 8);
    qA[1] = *(const v8s*)(qrow + 32 + lg * 8);
  }

  v4f O[4];
  v4f zero = {0.f, 0.f, 0.f, 0.f};
#pragma unroll
  for (int d = 0; d < 4; ++d) O[d] = zero;
  float mrun = -1e30f, lrun = 0.f;

  // prologue: tile 0 into regs
  int4 gK0 = *(const int4*)(Kg0);
  int4 gK1 = *(const int4*)(Kg0 + 4096);
  int2 vlo0 = *(const int2*)(Vg0);
  int2 vhi0 = *(const int2*)(Vg0 + 64);
  int2 vlo1 = *(const int2*)(Vg0 + 32 * T_SEQ);
  int2 vhi1 = *(const int2*)(Vg0 + 32 * T_SEQ + 64);

  for (int t = 0; t <= qc; ++t) {
    __syncthreads();  // all reads of previous tile done
    *(int4*)(KsB + kLds0) = gK0;
    *(int4*)(KsB + kLds0 + 8192) = gK1;
    {
      int4 v0; v0.x = vlo0.x; v0.y = vlo0.y; v0.z = vhi0.x; v0.w = vhi0.y;
      int4 v1; v1.x = vlo1.x; v1.y = vlo1.y; v1.z = vhi1.x; v1.w = vhi1.y;
      *(int4*)(VtB + vLds0) = v0;
      *(int4*)(VtB + vLds0 + 8192) = v1;
    }
    __syncthreads();
    if (t < qc) {  // prefetch next tile (hidden under compute, T14)
      const unsigned short* kp = Kg0 + (t + 1) * (128 * HS);
      gK0 = *(const int4*)kp;
      gK1 = *(const int4*)(kp + 4096);
      const unsigned short* vp = Vg0 + (t + 1) * 128;
      vlo0 = *(const int2*)(vp);
      vhi0 = *(const int2*)(vp + 64);
      vlo1 = *(const int2*)(vp + 32 * T_SEQ);
      vhi1 = *(const int2*)(vp + 32 * T_SEQ + 64);
    }

    const int cflim = (t == qc) ? w : 7;          // wave-uniform

    // S^T = K Q^T : lane q = w*16+lr; S[cf][r] at kv = cf*16+lg*4+r
    v4f S[8];
    __builtin_amdgcn_s_setprio(1);
#pragma unroll
    for (int cf = 0; cf < 8; ++cf) {
      if (cf <= cflim) {
        S[cf] = zero;
#pragma unroll
        for (int ks = 0; ks < 2; ++ks) {
          int srow = cf * 16 + lr;
          v8s kb = *(const v8s*)(KsB + srow * 128 +
                                 ((((ks << 2) + lg) ^ (lr & 7)) << 4));
          S[cf] = __builtin_amdgcn_mfma_f32_16x16x32_bf16(kb, qA[ks], S[cf], 0, 0, 0);
        }
      } else {
        S[cf] = (v4f){-1e30f, -1e30f, -1e30f, -1e30f};
      }
    }
    __builtin_amdgcn_s_setprio(0);

    if (t == qc) {  // causal mask: only cf==w block straddles the diagonal
#pragma unroll
      for (int cf = 0; cf < 8; ++cf)
        if (cf == w) {
#pragma unroll
          for (int r = 0; r < 4; ++r)
            if (lg * 4 + r > lr) S[cf][r] = -1e30f;
        }
    }

    // per-lane online softmax (exp2 domain; q fixed = lr)
    float mx = -1e30f;
#pragma unroll
    for (int cf = 0; cf < 8; ++cf)
#pragma unroll
      for (int r = 0; r < 4; ++r) mx = fmaxf(mx, S[cf][r]);
    mx = fmaxf(mx, __shfl_xor(mx, 16));
    mx = fmaxf(mx, __shfl_xor(mx, 32));

    if (!__all(mx - mrun <= 8.0f)) {     // defer-max (T13, THR=8)
      float mn = fmaxf(mrun, mx);
      float alpha = exp2_fast(mrun - mn);
      mrun = mn;
      lrun *= alpha;
#pragma unroll
      for (int df = 0; df < 4; ++df)
#pragma unroll
        for (int r = 0; r < 4; ++r) O[df][r] *= alpha;
    }

    float sum = 0.f;
#pragma unroll
    for (int cf = 0; cf < 8; ++cf)
#pragma unroll
      for (int r = 0; r < 4; ++r) {
        float p = exp2_fast(S[cf][r] - mrun);
        S[cf][r] = p;
        sum += p;
      }
    sum += __shfl_xor(sum, 16);
    sum += __shfl_xor(sum, 32);
    lrun += sum;

    // pack P rows to bf16 pairs (lane-local; feeds PV B-frag directly)
    unsigned pk0[8], pk1[8];
#pragma unroll
    for (int cf = 0; cf < 8; ++cf) {
      pk0[cf] = cvt_pk_bf16(S[cf][0], S[cf][1]);
      pk1[cf] = cvt_pk_bf16(S[cf][2], S[cf][3]);
    }

    // O^T += V^T P^T with custom k-mapping: call c = kv blocks {c, c+4}
    __builtin_amdgcn_s_setprio(1);
#pragma unroll
    for (int c = 0; c < 4; ++c) {
      if (t != qc || c <= w) {
        union { unsigned u[4]; v8s s; } pu;
        pu.u[0] = pk0[c]; pu.u[1] = pk1[c];
        pu.u[2] = pk0[c + 4]; pu.u[3] = pk1[c + 4];
        v8s pa = pu.s;
#pragma unroll
        for (int df = 0; df < 4; ++df) {
          int d = df * 16 + lr;
          v8s va = *(const v8s*)(VtB + d * 256 +
                                 ((((c << 2) + lg) ^ lr) << 4));
          O[df] = __builtin_amdgcn_mfma_f32_16x16x32_bf16(va, pa, O[df], 0, 0, 0);
        }
      }
    }
    __builtin_amdgcn_s_setprio(0);
  }

  // epilogue: lane owns q-row tq; d = df*16+lg*4+r -> 4 consecutive bf16
  float invl = 1.0f / lrun;
  int tq = qc * 128 + w * 16 + lr;
  int b = bh >> 4, h = bh & 15;
  size_t ybase = ((size_t)b * T_SEQ + tq) * (NH * HS) + h * 64;
#pragma unroll
  for (int df = 0; df < 4; ++df) {
    ushort4 o4;
    o4.x = f2bf(O[df][0] * invl);
    o4.y = f2bf(O[df][1] * invl);
    o4.z = f2bf(O[df][2] * invl);
    o4.w = f2bf(O[df][3] * invl);
    *(ushort4*)(Yg + ybase + df * 16 + lg * 4) = o4;
  }
}

extern "C" void kernel_launch(void* const* d_in, const int* in_sizes, int n_in,
                              void* d_out, int out_size, void* d_ws, size_t ws_size,
                              hipStream_t stream) {
  (void)in_sizes; (void)n_in; (void)out_size; (void)ws_size;
  const float* x  = (const float*)d_in[0];
  const float* Wq = (const float*)d_in[1];
  const float* Wk = (const float*)d_in[2];
  const float* Wv = (const float*)d_in[3];
  const float* Wo = (const float*)d_in[4];
  const float* bo = (const float*)d_in[5];

  unsigned char* ws = (unsigned char*)d_ws;
  unsigned short* xb  = (unsigned short*)(ws);                      // 8MB
  unsigned short* Wt  = (unsigned short*)(ws + (8u << 20));         // 6MB
  unsigned short* Wot = (unsigned short*)(ws + (14u << 20));        // 2MB
  unsigned short* qkv = (unsigned short*)(ws + (16u << 20));        // 24MB
  unsigned short* Y   = (unsigned short*)(ws + (40u << 20));        // 8MB

  // 1. x -> bf16
  cvt_f32_bf16x4<<<4096, 256, 0, stream>>>(x, xb, (MROWS * CEMB) / 4);

  // 2. weights -> bf16, transposed to [N][K]
  dim3 tb(32, 8);
  transpose_cvt<<<dim3(2, 32, 16), tb, 0, stream>>>(Wq, Wt, 1024, 64);
  transpose_cvt<<<dim3(2, 32, 16), tb, 0, stream>>>(Wk, Wt + (1u << 20), 1024, 64);
  transpose_cvt<<<dim3(2, 32, 16), tb, 0, stream>>>(Wv, Wt + (2u << 20), 1024, 64);
  transpose_cvt<<<dim3(32, 32, 1), tb, 0, stream>>>(Wo, Wot, 1024, 1024);

  // 3. fused QKV projection: [4096][1024] x [3072][1024]^T  (1536 blocks)
  gemm_bt64<0><<<dim3(1536), 256, 0, stream>>>(xb, Wt, qkv, nullptr, 24);

  // 4. causal flash attention (V pre-transposed per head: [b][h][64][2048])
  const unsigned short* Qp = qkv;
  const unsigned short* Kp = qkv + (size_t)B_SZ * NH * T_SEQ * HS;
  const unsigned short* Vtp = qkv + (size_t)2 * B_SZ * NH * T_SEQ * HS;
  attn_kernel<<<dim3(512), 512, 0, stream>>>(Qp, Kp, Vtp, Y);

  // 5. output projection + bias -> f32 d_out  (512 blocks)
  gemm_bt64<1><<<dim3(512), 256, 0, stream>>>(Y, Wot, d_out, bo, 8);
}

// Round 7
// 110.819 us; speedup vs baseline: 1.1775x; 1.1775x over previous
//
#include <hip/hip_runtime.h>

// MHA forward, full-bf16 MFMA pipeline.
// ws layout (bytes): xb[8MB] | Wt[6MB: [3][1024][1024] bf16 N-major] | Wot[2MB]
//                    | qkv[24MB: Q,K:[B][H][T][64], V:[B][H][64][T]] | Y[8MB]

typedef short v8s __attribute__((ext_vector_type(8)));
typedef float v4f __attribute__((ext_vector_type(4)));

#define DEVI __device__ __forceinline__

#define B_SZ 2
#define T_SEQ 2048
#define NH 16
#define HS 64
#define CEMB 1024
#define MROWS (B_SZ * T_SEQ)   // 4096
#define KSZ 1024
// Q scale: 1/sqrt(64) * log2(e)  (attention softmax runs in exp2 domain)
#define SCALE_Q 0.18033688011112042f

DEVI unsigned short f2bf(float f) {
  union { float f; unsigned u; } c; c.f = f;
  unsigned u = c.u;
  unsigned r = (u + 0x7FFFu + ((u >> 16) & 1u)) >> 16;   // RNE
  return (unsigned short)r;
}

DEVI float exp2_fast(float x) {         // v_exp_f32 = 2^x
  float r;
  asm("v_exp_f32 %0, %1" : "=v"(r) : "v"(x));
  return r;
}

DEVI unsigned cvt_pk_bf16(float lo, float hi) {  // packs 2 f32 -> 2 bf16
  unsigned r;
  asm("v_cvt_pk_bf16_f32 %0, %1, %2" : "=v"(r) : "v"(lo), "v"(hi));
  return r;
}

// async global -> LDS, 16B per lane (wave-uniform LDS base + lane*16)
DEVI void gload_lds16(const void* g, void* l) {
  __builtin_amdgcn_global_load_lds(
      (const __attribute__((address_space(1))) void*)g,
      (__attribute__((address_space(3))) void*)l, 16, 0, 0);
}

// bijective XCD-contiguous block swizzle (requires nwg % 8 == 0)
DEVI int xcd_swz(int bid, int nwg) {
  int q = nwg >> 3;
  return (bid & 7) * q + (bid >> 3);
}

// ---------------- fused prep: x->bf16 + weight transposes (1 launch) -------
// blocks [0,2048): x cvt (8 elems/thread)
// blocks [2048,5120): Wq/Wk/Wv transpose f32[1024][64]/head -> bf16[64][1024]
// blocks [5120,6144): Wo transpose f32[1024][1024] -> bf16[1024][1024]
__global__ __launch_bounds__(256, 4) void prep_kernel(
    const float* __restrict__ x, const float* __restrict__ Wq,
    const float* __restrict__ Wk, const float* __restrict__ Wv,
    const float* __restrict__ Wo, unsigned short* __restrict__ xb,
    unsigned short* __restrict__ Wt, unsigned short* __restrict__ Wot) {
  int bid = blockIdx.x;
  if (bid < 2048) {
    int i = bid * 2048 + threadIdx.x * 8;
    float4 a = *(const float4*)(x + i);
    float4 b = *(const float4*)(x + i + 4);
    ushort4 o0, o1;
    o0.x = f2bf(a.x); o0.y = f2bf(a.y); o0.z = f2bf(a.z); o0.w = f2bf(a.w);
    o1.x = f2bf(b.x); o1.y = f2bf(b.y); o1.z = f2bf(b.z); o1.w = f2bf(b.w);
    *(ushort4*)(xb + i) = o0;
    *(ushort4*)(xb + i + 4) = o1;
    return;
  }
  __shared__ float tile[32][33];
  const float* in; unsigned short* out;
  int C, bx, by;
  if (bid < 5120) {
    int b2 = bid - 2048;
    int widx = b2 >> 10, rem = b2 & 1023;
    in = (widx == 0 ? Wq : (widx == 1 ? Wk : Wv));
    int z = rem >> 6;                     // head 0..15
    bx = rem & 1; by = (rem >> 1) & 31;
    C = 64;
    in += (size_t)z * 1024 * 64;
    out = Wt + ((size_t)widx << 20) + (size_t)z * 1024 * 64;
  } else {
    int rem = bid - 5120;
    C = 1024;
    bx = rem & 31; by = rem >> 5;
    in = Wo; out = Wot;
  }
  int c0 = bx * 32, r0 = by * 32;
  int tx = threadIdx.x & 31, ty = threadIdx.x >> 5;
#pragma unroll
  for (int j = 0; j < 4; ++j)
    tile[ty + j * 8][tx] = in[(size_t)(r0 + ty + j * 8) * C + c0 + tx];
  __syncthreads();
#pragma unroll
  for (int j = 0; j < 4; ++j)
    out[(size_t)(c0 + ty + j * 8) * 1024 + r0 + tx] = f2bf(tile[tx][ty + j * 8]);
}

// ------------- GEMM: C = A[M][1024] x Bt[N][1024]^T, bf16 in, f32 acc -------
// 128x128 tile, BK=32, 4 waves; 3-deep counted-vmcnt pipeline (round-5 proven):
// {vmcnt(8); s_barrier; compute; lgkmcnt(0); s_barrier; STAGE(t+3)}.
// 1D grid + bijective XCD swizzle, N-fastest within chunk (A panels L2-local).
// LDS linear for global_load_lds; source chunk pre-swizzled (c ^= row&3) and
// same XOR on fragment reads.
// MODE 0: QKV epilogue -> bf16 scatter; Q scaled by SCALE_Q; V transposed
//         (Q,K: [b][h][t][d], V: [b][h][d][t])
// MODE 1: out-proj epilogue -> f32 [M][1024] + bias
template <int MODE>
__global__ __launch_bounds__(256, 3) void gemm_bt(
    const unsigned short* __restrict__ A, const unsigned short* __restrict__ Bt,
    void* __restrict__ Cout, const float* __restrict__ bias, int nbx) {
  __shared__ __align__(16) unsigned short As[3][128 * 32];   // 8KB x3
  __shared__ __align__(16) unsigned short Bs[3][128 * 32];   // 8KB x3

  const int tid = threadIdx.x;
  const int lane = tid & 63, w = tid >> 6;
  const int wm = w >> 1, wn = w & 1;
  const int lr = lane & 15, lg = lane >> 4;

  const int wg = xcd_swz(blockIdx.x, gridDim.x);
  const int mb = (wg / nbx) * 128, nb = (wg % nbx) * 128;  // N-fastest in chunk

  v4f acc[4][4];
  v4f zero = {0.f, 0.f, 0.f, 0.f};
#pragma unroll
  for (int i = 0; i < 4; ++i)
#pragma unroll
    for (int j = 0; j < 4; ++j) acc[i][j] = zero;

  // staging: wave w covers tile rows w*32..w*32+31 (2 issues/matrix, 16 rows ea)
  // lane -> row = base + (lane>>2); fetches global chunk (lane&3)^(row&3)
  const int srow = lane >> 2;
  const int sgcol = ((lane & 3) ^ (srow & 3)) * 8;
  const unsigned short* gA = A + (size_t)(mb + w * 32 + srow) * KSZ + sgcol;
  const unsigned short* gB = Bt + (size_t)(nb + w * 32 + srow) * KSZ + sgcol;
  unsigned short* lA = &As[0][0] + w * 1024;   // wave-uniform; +4096/buf
  unsigned short* lB = &Bs[0][0] + w * 1024;

#define STAGE_G(buf, kb)                                        \
  do {                                                          \
    gload_lds16(gA + (kb), lA + (buf) * 4096);                  \
    gload_lds16(gA + (kb) + 16 * KSZ, lA + (buf) * 4096 + 512); \
    gload_lds16(gB + (kb), lB + (buf) * 4096);                  \
    gload_lds16(gB + (kb) + 16 * KSZ, lB + (buf) * 4096 + 512); \
  } while (0)

  // prologue: 3 tiles in flight (12 loads)
  STAGE_G(0, 0);
  STAGE_G(1, 32);
  STAGE_G(2, 64);

  const int NT = KSZ / 32;   // 32 K-steps
  for (int t = 0; t < NT; ++t) {
    // tile t's 4 loads complete (t+1, t+2 still outstanding: 8)
    asm volatile("s_waitcnt vmcnt(8)" ::: "memory");
    __builtin_amdgcn_s_barrier();

    const int buf = t % 3;
    v8s af[4], bfr[4];
#pragma unroll
    for (int i = 0; i < 4; ++i) {
      int ra = wm * 64 + i * 16 + lr, rb = wn * 64 + i * 16 + lr;
      af[i]  = *(const v8s*)&As[buf][ra * 32 + ((lg ^ (lr & 3)) << 3)];
      bfr[i] = *(const v8s*)&Bs[buf][rb * 32 + ((lg ^ (lr & 3)) << 3)];
    }
#pragma unroll
    for (int i = 0; i < 4; ++i)
#pragma unroll
      for (int j = 0; j < 4; ++j)
        acc[i][j] = __builtin_amdgcn_mfma_f32_16x16x32_bf16(af[i], bfr[j], acc[i][j], 0, 0, 0);

    // all waves done reading buf before overwriting it with tile t+3
    asm volatile("s_waitcnt lgkmcnt(0)" ::: "memory");
    __builtin_amdgcn_s_barrier();
    if (t + 3 < NT) STAGE_G(buf, (t + 3) * 32);
  }
#undef STAGE_G

#pragma unroll
  for (int i = 0; i < 4; ++i) {
    int mrow0 = mb + wm * 64 + i * 16 + lg * 4;
#pragma unroll
    for (int j = 0; j < 4; ++j) {
      int ncol = nb + wn * 64 + j * 16 + lr;
      if (MODE == 0) {
        int p = ncol >> 10, rem = ncol & 1023, h = rem >> 6, d = rem & 63;
        float sc = (p == 0) ? SCALE_Q : 1.0f;
        unsigned short* out = (unsigned short*)Cout;
#pragma unroll
        for (int r = 0; r < 4; ++r) {
          int mrow = mrow0 + r;
          int b = mrow >> 11, t = mrow & 2047;
          size_t off;
          if (p < 2)
            off = ((size_t)((p * B_SZ + b) * NH + h) * T_SEQ + t) * HS + d;
          else  // V transposed: [b][h][d][t]
            off = (size_t)(2 * B_SZ * NH) * T_SEQ * HS +
                  ((size_t)(b * NH + h) * HS + d) * T_SEQ + t;
          out[off] = f2bf(acc[i][j][r] * sc);
        }
      } else {
        float* out = (float*)Cout;
        float bv = bias[ncol];
#pragma unroll
        for (int r = 0; r < 4; ++r)
          out[(size_t)(mrow0 + r) * CEMB + ncol] = acc[i][j][r] + bv;
      }
    }
  }
}

// ------------- causal flash attention, swapped-operand, reg-P -------------
// 512 threads = 8 waves; wave w owns q rows qc*128 + w*16 .. +15.
// mfma(K,Q) -> S^T: lane owns ONE q-row (q=w*16+lr), kv = cf*16+lg*4+r.
// PV uses a CUSTOM k-slot mapping (valid since A/B frags share (lg,j)->k and
// sum over k is order-invariant): call c covers kv in [c*16,c*16+16) u
// [c*16+64,c*16+80); B-frag = lane-local packed {pk(S[c]),pk(S[c+4])} (NO
// cross-lane exchange, no P LDS); A-frag contiguous via permuted V layout.
__global__ __launch_bounds__(512, 4) void attn_kernel(
    const unsigned short* __restrict__ Qg, const unsigned short* __restrict__ Kg,
    const unsigned short* __restrict__ Vtg, unsigned short* __restrict__ Yg) {
  __shared__ __align__(16) unsigned char lds[32 * 1024];
  unsigned char* KsB = lds;             // 16KB [128 s][64 d], chunk-swizzled
  unsigned char* VtB = lds + 16384;     // 16KB [64 d][128 col'], swizzled

  const int tid = threadIdx.x;
  const int lane = tid & 63, w = tid >> 6;
  const int lr = lane & 15, lg = lane >> 4;
  const int qc = 15 - (blockIdx.x >> 5);   // LPT: longest q-chunk first
  const int bh = blockIdx.x & 31;

  const unsigned short* Qbase = Qg + (size_t)bh * T_SEQ * HS;
  const unsigned short* Kbase = Kg + (size_t)bh * T_SEQ * HS;
  const unsigned short* Vtbase = Vtg + (size_t)bh * T_SEQ * HS;  // [64][2048]

  // K staging geometry
  const int ks_row = tid >> 3, ks_cb = tid & 7;
  const int kLds0 = ks_row * 128 + ((ks_cb ^ (ks_row & 7)) << 4);
  const unsigned short* Kg0 = Kbase + ks_row * HS + ks_cb * 8;
  // V staging: thread (vs_d, m) handles col'-chunk m of rows vs_d, vs_d+32
  const int vs_d = tid >> 4, vs_m = tid & 15;
  const int vLds0 = vs_d * 256 + ((vs_m ^ (vs_d & 15)) << 4);
  const int vbt = ((vs_m >> 2) << 4) + ((vs_m & 3) << 2);  // t-offset of 4-group
  const unsigned short* Vg0 = Vtbase + (size_t)vs_d * T_SEQ + vbt;

  // Q fragment (B-operand): lane lr -> q row, lg*8 k-offset
  v8s qA[2];
  {
    const unsigned short* qrow = Qbase + (size_t)(qc * 128 + w * 16 + lr) * HS;
    qA[0] = *(const v8s*)(qrow + lg * 8);
    qA[1] = *(const v8s*)(qrow + 32 + lg * 8);
  }

  v4f O[4];
  v4f zero = {0.f, 0.f, 0.f, 0.f};
#pragma unroll
  for (int d = 0; d < 4; ++d) O[d] = zero;
  float mrun = -1e30f, lrun = 0.f;

  // prologue: tile 0 into regs
  int4 gK0 = *(const int4*)(Kg0);
  int4 gK1 = *(const int4*)(Kg0 + 4096);
  int2 vlo0 = *(const int2*)(Vg0);
  int2 vhi0 = *(const int2*)(Vg0 + 64);
  int2 vlo1 = *(const int2*)(Vg0 + 32 * T_SEQ);
  int2 vhi1 = *(const int2*)(Vg0 + 32 * T_SEQ + 64);

  for (int t = 0; t <= qc; ++t) {
    __syncthreads();  // all reads of previous tile done
    *(int4*)(KsB + kLds0) = gK0;
    *(int4*)(KsB + kLds0 + 8192) = gK1;
    {
      int4 v0; v0.x = vlo0.x; v0.y = vlo0.y; v0.z = vhi0.x; v0.w = vhi0.y;
      int4 v1; v1.x = vlo1.x; v1.y = vlo1.y; v1.z = vhi1.x; v1.w = vhi1.y;
      *(int4*)(VtB + vLds0) = v0;
      *(int4*)(VtB + vLds0 + 8192) = v1;
    }
    __syncthreads();
    if (t < qc) {  // prefetch next tile (hidden under compute, T14)
      const unsigned short* kp = Kg0 + (t + 1) * (128 * HS);
      gK0 = *(const int4*)kp;
      gK1 = *(const int4*)(kp + 4096);
      const unsigned short* vp = Vg0 + (t + 1) * 128;
      vlo0 = *(const int2*)(vp);
      vhi0 = *(const int2*)(vp + 64);
      vlo1 = *(const int2*)(vp + 32 * T_SEQ);
      vhi1 = *(const int2*)(vp + 32 * T_SEQ + 64);
    }

    const int cflim = (t == qc) ? w : 7;          // wave-uniform

    // S^T = K Q^T : lane q = w*16+lr; S[cf][r] at kv = cf*16+lg*4+r
    v4f S[8];
    __builtin_amdgcn_s_setprio(1);
#pragma unroll
    for (int cf = 0; cf < 8; ++cf) {
      if (cf <= cflim) {
        S[cf] = zero;
#pragma unroll
        for (int ks = 0; ks < 2; ++ks) {
          int srow = cf * 16 + lr;
          v8s kb = *(const v8s*)(KsB + srow * 128 +
                                 ((((ks << 2) + lg) ^ (lr & 7)) << 4));
          S[cf] = __builtin_amdgcn_mfma_f32_16x16x32_bf16(kb, qA[ks], S[cf], 0, 0, 0);
        }
      } else {
        S[cf] = (v4f){-1e30f, -1e30f, -1e30f, -1e30f};
      }
    }
    __builtin_amdgcn_s_setprio(0);

    if (t == qc) {  // causal mask: only cf==w block straddles the diagonal
#pragma unroll
      for (int cf = 0; cf < 8; ++cf)
        if (cf == w) {
#pragma unroll
          for (int r = 0; r < 4; ++r)
            if (lg * 4 + r > lr) S[cf][r] = -1e30f;
        }
    }

    // per-lane online softmax (exp2 domain; q fixed = lr)
    float mx = -1e30f;
#pragma unroll
    for (int cf = 0; cf < 8; ++cf)
#pragma unroll
      for (int r = 0; r < 4; ++r) mx = fmaxf(mx, S[cf][r]);
    mx = fmaxf(mx, __shfl_xor(mx, 16));
    mx = fmaxf(mx, __shfl_xor(mx, 32));

    if (!__all(mx - mrun <= 8.0f)) {     // defer-max (T13, THR=8)
      float mn = fmaxf(mrun, mx);
      float alpha = exp2_fast(mrun - mn);
      mrun = mn;
      lrun *= alpha;
#pragma unroll
      for (int df = 0; df < 4; ++df)
#pragma unroll
        for (int r = 0; r < 4; ++r) O[df][r] *= alpha;
    }

    float sum = 0.f;
#pragma unroll
    for (int cf = 0; cf < 8; ++cf)
#pragma unroll
      for (int r = 0; r < 4; ++r) {
        float p = exp2_fast(S[cf][r] - mrun);
        S[cf][r] = p;
        sum += p;
      }
    sum += __shfl_xor(sum, 16);
    sum += __shfl_xor(sum, 32);
    lrun += sum;

    // pack P rows to bf16 pairs (lane-local; feeds PV B-frag directly)
    unsigned pk0[8], pk1[8];
#pragma unroll
    for (int cf = 0; cf < 8; ++cf) {
      pk0[cf] = cvt_pk_bf16(S[cf][0], S[cf][1]);
      pk1[cf] = cvt_pk_bf16(S[cf][2], S[cf][3]);
    }

    // O^T += V^T P^T with custom k-mapping: call c = kv blocks {c, c+4}
    __builtin_amdgcn_s_setprio(1);
#pragma unroll
    for (int c = 0; c < 4; ++c) {
      if (t != qc || c <= w) {
        union { unsigned u[4]; v8s s; } pu;
        pu.u[0] = pk0[c]; pu.u[1] = pk1[c];
        pu.u[2] = pk0[c + 4]; pu.u[3] = pk1[c + 4];
        v8s pa = pu.s;
#pragma unroll
        for (int df = 0; df < 4; ++df) {
          int d = df * 16 + lr;
          v8s va = *(const v8s*)(VtB + d * 256 +
                                 ((((c << 2) + lg) ^ lr) << 4));
          O[df] = __builtin_amdgcn_mfma_f32_16x16x32_bf16(va, pa, O[df], 0, 0, 0);
        }
      }
    }
    __builtin_amdgcn_s_setprio(0);
  }

  // epilogue: lane owns q-row tq; d = df*16+lg*4+r -> 4 consecutive bf16
  float invl = 1.0f / lrun;
  int tq = qc * 128 + w * 16 + lr;
  int b = bh >> 4, h = bh & 15;
  size_t ybase = ((size_t)b * T_SEQ + tq) * (NH * HS) + h * 64;
#pragma unroll
  for (int df = 0; df < 4; ++df) {
    ushort4 o4;
    o4.x = f2bf(O[df][0] * invl);
    o4.y = f2bf(O[df][1] * invl);
    o4.z = f2bf(O[df][2] * invl);
    o4.w = f2bf(O[df][3] * invl);
    *(ushort4*)(Yg + ybase + df * 16 + lg * 4) = o4;
  }
}

extern "C" void kernel_launch(void* const* d_in, const int* in_sizes, int n_in,
                              void* d_out, int out_size, void* d_ws, size_t ws_size,
                              hipStream_t stream) {
  (void)in_sizes; (void)n_in; (void)out_size; (void)ws_size;
  const float* x  = (const float*)d_in[0];
  const float* Wq = (const float*)d_in[1];
  const float* Wk = (const float*)d_in[2];
  const float* Wv = (const float*)d_in[3];
  const float* Wo = (const float*)d_in[4];
  const float* bo = (const float*)d_in[5];

  unsigned char* ws = (unsigned char*)d_ws;
  unsigned short* xb  = (unsigned short*)(ws);                      // 8MB
  unsigned short* Wt  = (unsigned short*)(ws + (8u << 20));         // 6MB
  unsigned short* Wot = (unsigned short*)(ws + (14u << 20));        // 2MB
  unsigned short* qkv = (unsigned short*)(ws + (16u << 20));        // 24MB
  unsigned short* Y   = (unsigned short*)(ws + (40u << 20));        // 8MB

  // 1. fused prep: x->bf16 + all weight transposes (one launch)
  prep_kernel<<<dim3(6144), 256, 0, stream>>>(x, Wq, Wk, Wv, Wo, xb, Wt, Wot);

  // 2. fused QKV projection: [4096][1024] x [3072][1024]^T (768 blocks)
  gemm_bt<0><<<dim3(768), 256, 0, stream>>>(xb, Wt, qkv, nullptr, 24);

  // 3. causal flash attention (V pre-transposed per head: [b][h][64][2048])
  const unsigned short* Qp = qkv;
  const unsigned short* Kp = qkv + (size_t)B_SZ * NH * T_SEQ * HS;
  const unsigned short* Vtp = qkv + (size_t)2 * B_SZ * NH * T_SEQ * HS;
  attn_kernel<<<dim3(512), 512, 0, stream>>>(Qp, Kp, Vtp, Y);

  // 4. output projection + bias -> f32 d_out (256 blocks)
  gemm_bt<1><<<dim3(256), 256, 0, stream>>>(Y, Wot, d_out, bo, 8);
}